// Round 1
// baseline (1655.753 us; speedup 1.0000x reference)
//
#include <hip/hip_runtime.h>

// ALISTA on MI355X.
// d_{k+1} = soft(d_k - s*(d_k @ P - C), thr_k),  P = A^T W [2048x2048], C = y W [4096x2048]
// P kept as fp16 split (Ph + Plx/256); d_k kept as fp16 scaled by 4^-(k-1).

#define NDIM 2048
#define MDIM 512
#define BATCHN 4096
#define NITER 16
#define BM 128
#define BN 128
#define BK 64

typedef _Float16 f16;
typedef f16 f16x8 __attribute__((ext_vector_type(8)));
typedef float f32x4 __attribute__((ext_vector_type(4)));

__device__ __forceinline__ void gload_lds16(const void* g, void* lds) {
  __builtin_amdgcn_global_load_lds(
      (const __attribute__((address_space(1))) unsigned int*)g,
      (__attribute__((address_space(3))) unsigned int*)lds, 16, 0, 0);
}

// One K-pass of a TN GEMM: C[row,col] += sum_k A[row,k]*B[col,k].
// A: [Mrows, K] row-major (k contiguous), B: [Ncols, K] row-major (k contiguous).
__device__ __forceinline__ void gemm_pass(
    const f16* __restrict__ Ap, const f16* __restrict__ Bp, int K,
    int rowTile, int colTile, int t, int w, int l, int wr, int wc,
    f16* ldsA, f16* ldsB, f32x4 (&acc)[4][4])
{
  const f16* Arow = Ap + (size_t)rowTile * K;
  const f16* Brow = Bp + (size_t)colTile * K;
  for (int kt = 0; kt < K; kt += BK) {
    __syncthreads();  // protect LDS overwrite
#pragma unroll
    for (int n = 0; n < 4; ++n) {  // stage A tile [128][64] fp16, 16B/lane
      int e = n * 2048 + t * 8;
      int r = e >> 6, c = e & 63;
      gload_lds16(Arow + (size_t)r * K + kt + c, (char*)ldsA + n * 4096 + w * 1024);
    }
#pragma unroll
    for (int n = 0; n < 4; ++n) {  // stage B tile [128][64]
      int e = n * 2048 + t * 8;
      int r = e >> 6, c = e & 63;
      gload_lds16(Brow + (size_t)r * K + kt + c, (char*)ldsB + n * 4096 + w * 1024);
    }
    asm volatile("s_waitcnt vmcnt(0)" ::: "memory");
    __syncthreads();  // tile ready
#pragma unroll
    for (int ks = 0; ks < 2; ++ks) {
      f16x8 a[4], b[4];
#pragma unroll
      for (int m = 0; m < 4; ++m)
        a[m] = *(const f16x8*)(ldsA + ((wr * 64 + m * 16 + (l & 15)) * BK + ks * 32 + (l >> 4) * 8));
#pragma unroll
      for (int n = 0; n < 4; ++n)
        b[n] = *(const f16x8*)(ldsB + ((wc * 64 + n * 16 + (l & 15)) * BK + ks * 32 + (l >> 4) * 8));
#pragma unroll
      for (int m = 0; m < 4; ++m)
#pragma unroll
        for (int n = 0; n < 4; ++n)
          acc[m][n] = __builtin_amdgcn_mfma_f32_16x16x32_f16(a[m], b[n], acc[m][n], 0, 0, 0);
    }
  }
}

// EPI 0: write fp16 split pair (Ph, 256*Pl).  Passes: (A0,B0)+(A1,B1) scaled 1/256, then (A2,B2).
// EPI 1: write f32.                            Same pass structure.
// EPI 2: ALISTA iteration epilogue.            Passes: (A0,B0) scaled 1/256, then (A1,B1).
template <int EPI>
__global__ __launch_bounds__(256, 2) void gemm_tn(
    const f16* __restrict__ A0, const f16* __restrict__ B0,
    const f16* __restrict__ A1, const f16* __restrict__ B1,
    const f16* __restrict__ A2, const f16* __restrict__ B2,
    int K,
    float* __restrict__ outF, f16* __restrict__ outH, f16* __restrict__ outLx,
    const f16* __restrict__ Dsk, const float* __restrict__ Cmat,
    const float* __restrict__ thr, const float* __restrict__ step, int it,
    float sigma, float inv_sigma, float inv_sigma_next,
    float* __restrict__ outIter, f16* __restrict__ DsNext)
{
  __shared__ __align__(16) f16 ldsA[BM * BK];
  __shared__ __align__(16) f16 ldsB[BN * BK];
  int t = threadIdx.x;
  int w = t >> 6, l = t & 63;
  int wr = w >> 1, wc = w & 1;
  int rowTile = blockIdx.y * BM;
  int colTile = blockIdx.x * BN;

  f32x4 acc[4][4] = {};

  if (EPI == 2) {
    gemm_pass(A0, B0, K, rowTile, colTile, t, w, l, wr, wc, ldsA, ldsB, acc);
#pragma unroll
    for (int m = 0; m < 4; ++m)
#pragma unroll
      for (int n = 0; n < 4; ++n)
        acc[m][n] *= (1.0f / 256.0f);
    gemm_pass(A1, B1, K, rowTile, colTile, t, w, l, wr, wc, ldsA, ldsB, acc);
  } else {
    gemm_pass(A0, B0, K, rowTile, colTile, t, w, l, wr, wc, ldsA, ldsB, acc);
    gemm_pass(A1, B1, K, rowTile, colTile, t, w, l, wr, wc, ldsA, ldsB, acc);
#pragma unroll
    for (int m = 0; m < 4; ++m)
#pragma unroll
      for (int n = 0; n < 4; ++n)
        acc[m][n] *= (1.0f / 256.0f);
    gemm_pass(A2, B2, K, rowTile, colTile, t, w, l, wr, wc, ldsA, ldsB, acc);
  }

  // epilogue. C/D layout: col = lane&15, row = 4*(lane>>4) + reg   [m89-verified]
  int baseRow = rowTile + wr * 64 + ((l >> 4) << 2);
  int baseCol = colTile + wc * 64 + (l & 15);
  float s = 0.f, tt = 0.f;
  size_t itOff = 0;
  if (EPI == 2) {
    s = step[it];
    tt = thr[it];
    itOff = (size_t)it * (size_t)BATCHN * NDIM;
  }
#pragma unroll
  for (int m = 0; m < 4; ++m)
#pragma unroll
    for (int n = 0; n < 4; ++n)
#pragma unroll
      for (int r = 0; r < 4; ++r) {
        int row = baseRow + m * 16 + r;
        int col = baseCol + n * 16;
        size_t g = (size_t)row * NDIM + col;
        float v = acc[m][n][r];
        if (EPI == 0) {
          f16 h = (f16)v;
          outH[g] = h;
          outLx[g] = (f16)((v - (float)h) * 256.0f);
        } else if (EPI == 1) {
          outF[g] = v;
        } else {
          float ds = (float)Dsk[g];
          float cv = Cmat[g];
          float z = sigma * (ds - s * (v - cv * inv_sigma));
          float az = __builtin_fabsf(z) - tt;
          float dn = az > 0.f ? (z > 0.f ? az : -az) : 0.f;
          outIter[itOff + g] = dn;
          DsNext[g] = (f16)(dn * inv_sigma_next);
        }
      }
}

// in [512,2048] f32 -> transposed fp16 splits [2048,512]: oh + olx/256
__global__ __launch_bounds__(256) void trans_split(
    const float* __restrict__ in, f16* __restrict__ oh, f16* __restrict__ olx)
{
  __shared__ float tile[64][65];
  int t = threadIdx.x;
  int tr = t >> 6;   // 0..3
  int tc = t & 63;   // 0..63
  int r0 = blockIdx.y * 64;  // input row base (m)
  int c0 = blockIdx.x * 64;  // input col base (n)
#pragma unroll
  for (int i = 0; i < 16; ++i) {
    int r = i * 4 + tr;
    tile[r][tc] = in[(size_t)(r0 + r) * NDIM + c0 + tc];
  }
  __syncthreads();
#pragma unroll
  for (int i = 0; i < 16; ++i) {
    int r = i * 4 + tr;
    float v = tile[tc][r];  // = in[r0+tc][c0+r]
    f16 h = (f16)v;
    size_t o = (size_t)(c0 + r) * MDIM + r0 + tc;
    oh[o] = h;
    olx[o] = (f16)((v - (float)h) * 256.0f);
  }
}

__global__ __launch_bounds__(256) void split_y(
    const float* __restrict__ in, f16* __restrict__ oh, f16* __restrict__ olx)
{
  size_t i = (size_t)blockIdx.x * 256 + threadIdx.x;
  float v = in[i];
  f16 h = (f16)v;
  oh[i] = h;
  olx[i] = (f16)((v - (float)h) * 256.0f);
}

// iterate 0: d1 = soft(s0*C, thr0); out[0] = d1; Ds1 = fp16(d1)  (sigma_1 = 1)
__global__ __launch_bounds__(256) void alista_iter0(
    const float* __restrict__ Cmat, const float* __restrict__ thr,
    const float* __restrict__ step, float* __restrict__ out, f16* __restrict__ Ds1)
{
  size_t i = (size_t)blockIdx.x * 256 + threadIdx.x;
  float s = step[0], tt = thr[0];
  float z = s * Cmat[i];
  float az = __builtin_fabsf(z) - tt;
  float dn = az > 0.f ? (z > 0.f ? az : -az) : 0.f;
  out[i] = dn;
  Ds1[i] = (f16)dn;
}

extern "C" void kernel_launch(void* const* d_in, const int* in_sizes, int n_in,
                              void* d_out, int out_size, void* d_ws, size_t ws_size,
                              hipStream_t stream)
{
  const float* y    = (const float*)d_in[0];
  const float* A    = (const float*)d_in[1];
  const float* W    = (const float*)d_in[2];
  const float* thr  = (const float*)d_in[3];
  const float* step = (const float*)d_in[4];
  float* out = (float*)d_out;
  char* ws = (char*)d_ws;

  // ws layout (80 MB total):
  f16*   Pht  = (f16*)(ws + 0);              // 8 MB   P^T hi  [2048,2048]
  f16*   Plxt = (f16*)(ws + (8ull  << 20));  // 8 MB   P^T lo*256
  float* Cm   = (float*)(ws + (16ull << 20));// 32 MB  C = yW  [4096,2048] f32
  f16*   DsA  = (f16*)(ws + (48ull << 20));  // 16 MB  d scaled fp16 (ping)
  f16*   DsB  = (f16*)(ws + (64ull << 20));  // 16 MB  (pong)
  // precompute temps aliased over DsA region (dead before Ds1 is written):
  f16* Wth  = (f16*)(ws + (48ull << 20));    // 2 MB  W^T hi   [2048,512]
  f16* Wtlx = (f16*)(ws + (50ull << 20));    // 2 MB  W^T lo*256
  f16* Ath  = (f16*)(ws + (52ull << 20));    // 2 MB  A^T hi   [2048,512]
  f16* Atlx = (f16*)(ws + (54ull << 20));    // 2 MB  A^T lo*256
  f16* yh   = (f16*)(ws + (56ull << 20));    // 4 MB  y hi     [4096,512]
  f16* ylx  = (f16*)(ws + (60ull << 20));    // 4 MB  y lo*256

  trans_split<<<dim3(32, 8), 256, 0, stream>>>(A, Ath, Atlx);
  trans_split<<<dim3(32, 8), 256, 0, stream>>>(W, Wth, Wtlx);
  split_y<<<(BATCHN * MDIM) / 256, 256, 0, stream>>>(y, yh, ylx);

  // P^T[j][i] = sum_m W[m,j] A[m,i] = Wt @ At^T  (split-3, K=512) -> Pht/Plxt
  gemm_tn<0><<<dim3(16, 16), 256, 0, stream>>>(
      Wth, Atlx, Wtlx, Ath, Wth, Ath, MDIM,
      nullptr, Pht, Plxt, nullptr, nullptr, nullptr, nullptr, 0,
      0.f, 0.f, 0.f, nullptr, nullptr);

  // C = y @ W  (split-3, K=512) -> f32
  gemm_tn<1><<<dim3(16, 32), 256, 0, stream>>>(
      yh, Wtlx, ylx, Wth, yh, Wth, MDIM,
      Cm, nullptr, nullptr, nullptr, nullptr, nullptr, nullptr, 0,
      0.f, 0.f, 0.f, nullptr, nullptr);

  alista_iter0<<<(BATCHN * NDIM) / 256, 256, 0, stream>>>(Cm, thr, step, out, DsA);

  // iterations 1..15: acc = Ds@Plxt/256 + Ds@Pht ~= Ds@P ; fused soft-threshold epilogue
  f16* cur = DsA;
  f16* nxt = DsB;
  float sigma = 1.0f;  // sigma_k = 4^(k-1)
  for (int it = 1; it < NITER; ++it) {
    gemm_tn<2><<<dim3(16, 32), 256, 0, stream>>>(
        cur, Plxt, cur, Pht, nullptr, nullptr, NDIM,
        nullptr, nullptr, nullptr, cur, Cm, thr, step, it,
        sigma, 1.0f / sigma, 0.25f / sigma, out, nxt);
    sigma *= 4.0f;
    f16* tmp = cur; cur = nxt; nxt = tmp;
  }
}

// Round 2
// 1046.558 us; speedup vs baseline: 1.5821x; 1.5821x over previous
//
#include <hip/hip_runtime.h>

// ALISTA on MI355X.
// d_{k+1} = soft(d_k - s*(d_k @ P - C), thr_k),  P = A^T W [2048x2048], C = y W [4096x2048]
// R2: iteration GEMM uses single-pass fp16 P (unbiased rounding, ~0.2-0.4% compounded error;
//     split-3 retained for P/C precompute). + XCD-aware block swizzle on iteration GEMM.
// d_k carried as fp16 scaled by 4^-(k-1).

#define NDIM 2048
#define MDIM 512
#define BATCHN 4096
#define NITER 16
#define BM 128
#define BN 128
#define BK 64

typedef _Float16 f16;
typedef f16 f16x8 __attribute__((ext_vector_type(8)));
typedef float f32x4 __attribute__((ext_vector_type(4)));

__device__ __forceinline__ void gload_lds16(const void* g, void* lds) {
  __builtin_amdgcn_global_load_lds(
      (const __attribute__((address_space(1))) unsigned int*)g,
      (__attribute__((address_space(3))) unsigned int*)lds, 16, 0, 0);
}

// One K-pass of a TN GEMM: C[row,col] += sum_k A[row,k]*B[col,k].
// A: [Mrows, K] row-major (k contiguous), B: [Ncols, K] row-major (k contiguous).
__device__ __forceinline__ void gemm_pass(
    const f16* __restrict__ Ap, const f16* __restrict__ Bp, int K,
    int rowTile, int colTile, int t, int w, int l, int wr, int wc,
    f16* ldsA, f16* ldsB, f32x4 (&acc)[4][4])
{
  const f16* Arow = Ap + (size_t)rowTile * K;
  const f16* Brow = Bp + (size_t)colTile * K;
  for (int kt = 0; kt < K; kt += BK) {
    __syncthreads();  // protect LDS overwrite
#pragma unroll
    for (int n = 0; n < 4; ++n) {  // stage A tile [128][64] fp16, 16B/lane
      int e = n * 2048 + t * 8;
      int r = e >> 6, c = e & 63;
      gload_lds16(Arow + (size_t)r * K + kt + c, (char*)ldsA + n * 4096 + w * 1024);
    }
#pragma unroll
    for (int n = 0; n < 4; ++n) {  // stage B tile [128][64]
      int e = n * 2048 + t * 8;
      int r = e >> 6, c = e & 63;
      gload_lds16(Brow + (size_t)r * K + kt + c, (char*)ldsB + n * 4096 + w * 1024);
    }
    asm volatile("s_waitcnt vmcnt(0)" ::: "memory");
    __syncthreads();  // tile ready
#pragma unroll
    for (int ks = 0; ks < 2; ++ks) {
      f16x8 a[4], b[4];
#pragma unroll
      for (int m = 0; m < 4; ++m)
        a[m] = *(const f16x8*)(ldsA + ((wr * 64 + m * 16 + (l & 15)) * BK + ks * 32 + (l >> 4) * 8));
#pragma unroll
      for (int n = 0; n < 4; ++n)
        b[n] = *(const f16x8*)(ldsB + ((wc * 64 + n * 16 + (l & 15)) * BK + ks * 32 + (l >> 4) * 8));
#pragma unroll
      for (int m = 0; m < 4; ++m)
#pragma unroll
        for (int n = 0; n < 4; ++n)
          acc[m][n] = __builtin_amdgcn_mfma_f32_16x16x32_f16(a[m], b[n], acc[m][n], 0, 0, 0);
    }
  }
}

// EPI 0: write fp16 split pair (Ph, 256*Pl).  Passes: (A0,B0)+(A1,B1) scaled 1/256, then (A2,B2).
// EPI 1: write f32.                            Same pass structure.
// EPI 2: ALISTA iteration epilogue.            Single pass (A0,B0).
template <int EPI>
__global__ __launch_bounds__(256, 2) void gemm_tn(
    const f16* __restrict__ A0, const f16* __restrict__ B0,
    const f16* __restrict__ A1, const f16* __restrict__ B1,
    const f16* __restrict__ A2, const f16* __restrict__ B2,
    int K,
    float* __restrict__ outF, f16* __restrict__ outH, f16* __restrict__ outLx,
    const f16* __restrict__ Dsk, const float* __restrict__ Cmat,
    const float* __restrict__ thr, const float* __restrict__ step, int it,
    float sigma, float inv_sigma, float inv_sigma_next,
    float* __restrict__ outIter, f16* __restrict__ DsNext)
{
  __shared__ __align__(16) f16 ldsA[BM * BK];
  __shared__ __align__(16) f16 ldsB[BN * BK];
  int t = threadIdx.x;
  int w = t >> 6, l = t & 63;
  int wr = w >> 1, wc = w & 1;
  int rowTile, colTile;
  if (EPI == 2) {
    // 1D grid of 512 blocks; XCD-aware bijective swizzle (512 % 8 == 0).
    int bid = blockIdx.x;
    int wgid = (bid & 7) * 64 + (bid >> 3);   // each XCD: 64 consecutive wgids
    rowTile = (wgid >> 4) * BM;               // 32 row tiles
    colTile = (wgid & 15) * BN;               // 16 col tiles
  } else {
    rowTile = blockIdx.y * BM;
    colTile = blockIdx.x * BN;
  }

  f32x4 acc[4][4] = {};

  if (EPI == 2) {
    gemm_pass(A0, B0, K, rowTile, colTile, t, w, l, wr, wc, ldsA, ldsB, acc);
  } else {
    gemm_pass(A0, B0, K, rowTile, colTile, t, w, l, wr, wc, ldsA, ldsB, acc);
    gemm_pass(A1, B1, K, rowTile, colTile, t, w, l, wr, wc, ldsA, ldsB, acc);
#pragma unroll
    for (int m = 0; m < 4; ++m)
#pragma unroll
      for (int n = 0; n < 4; ++n)
        acc[m][n] *= (1.0f / 256.0f);
    gemm_pass(A2, B2, K, rowTile, colTile, t, w, l, wr, wc, ldsA, ldsB, acc);
  }

  // epilogue. C/D layout: col = lane&15, row = 4*(lane>>4) + reg   [m89-verified]
  int baseRow = rowTile + wr * 64 + ((l >> 4) << 2);
  int baseCol = colTile + wc * 64 + (l & 15);
  float s = 0.f, tt = 0.f;
  size_t itOff = 0;
  if (EPI == 2) {
    s = step[it];
    tt = thr[it];
    itOff = (size_t)it * (size_t)BATCHN * NDIM;
  }
#pragma unroll
  for (int m = 0; m < 4; ++m)
#pragma unroll
    for (int n = 0; n < 4; ++n)
#pragma unroll
      for (int r = 0; r < 4; ++r) {
        int row = baseRow + m * 16 + r;
        int col = baseCol + n * 16;
        size_t g = (size_t)row * NDIM + col;
        float v = acc[m][n][r];
        if (EPI == 0) {
          f16 h = (f16)v;
          outH[g] = h;
          outLx[g] = (f16)((v - (float)h) * 256.0f);
        } else if (EPI == 1) {
          outF[g] = v;
        } else {
          float ds = (float)Dsk[g];
          float cv = Cmat[g];
          float z = sigma * (ds - s * (v - cv * inv_sigma));
          float az = __builtin_fabsf(z) - tt;
          float dn = az > 0.f ? (z > 0.f ? az : -az) : 0.f;
          outIter[itOff + g] = dn;
          DsNext[g] = (f16)(dn * inv_sigma_next);
        }
      }
}

// in [512,2048] f32 -> transposed fp16 splits [2048,512]: oh + olx/256
__global__ __launch_bounds__(256) void trans_split(
    const float* __restrict__ in, f16* __restrict__ oh, f16* __restrict__ olx)
{
  __shared__ float tile[64][65];
  int t = threadIdx.x;
  int tr = t >> 6;   // 0..3
  int tc = t & 63;   // 0..63
  int r0 = blockIdx.y * 64;  // input row base (m)
  int c0 = blockIdx.x * 64;  // input col base (n)
#pragma unroll
  for (int i = 0; i < 16; ++i) {
    int r = i * 4 + tr;
    tile[r][tc] = in[(size_t)(r0 + r) * NDIM + c0 + tc];
  }
  __syncthreads();
#pragma unroll
  for (int i = 0; i < 16; ++i) {
    int r = i * 4 + tr;
    float v = tile[tc][r];  // = in[r0+tc][c0+r]
    f16 h = (f16)v;
    size_t o = (size_t)(c0 + r) * MDIM + r0 + tc;
    oh[o] = h;
    olx[o] = (f16)((v - (float)h) * 256.0f);
  }
}

__global__ __launch_bounds__(256) void split_y(
    const float* __restrict__ in, f16* __restrict__ oh, f16* __restrict__ olx)
{
  size_t i = (size_t)blockIdx.x * 256 + threadIdx.x;
  float v = in[i];
  f16 h = (f16)v;
  oh[i] = h;
  olx[i] = (f16)((v - (float)h) * 256.0f);
}

// iterate 0: d1 = soft(s0*C, thr0); out[0] = d1; Ds1 = fp16(d1)  (sigma_1 = 1)
__global__ __launch_bounds__(256) void alista_iter0(
    const float* __restrict__ Cmat, const float* __restrict__ thr,
    const float* __restrict__ step, float* __restrict__ out, f16* __restrict__ Ds1)
{
  size_t i = (size_t)blockIdx.x * 256 + threadIdx.x;
  float s = step[0], tt = thr[0];
  float z = s * Cmat[i];
  float az = __builtin_fabsf(z) - tt;
  float dn = az > 0.f ? (z > 0.f ? az : -az) : 0.f;
  out[i] = dn;
  Ds1[i] = (f16)dn;
}

extern "C" void kernel_launch(void* const* d_in, const int* in_sizes, int n_in,
                              void* d_out, int out_size, void* d_ws, size_t ws_size,
                              hipStream_t stream)
{
  const float* y    = (const float*)d_in[0];
  const float* A    = (const float*)d_in[1];
  const float* W    = (const float*)d_in[2];
  const float* thr  = (const float*)d_in[3];
  const float* step = (const float*)d_in[4];
  float* out = (float*)d_out;
  char* ws = (char*)d_ws;

  // ws layout (80 MB total):
  f16*   Pht  = (f16*)(ws + 0);              // 8 MB   P^T hi  [2048,2048]
  f16*   Plxt = (f16*)(ws + (8ull  << 20));  // 8 MB   P^T lo*256 (unused in iters; kept for EPI0)
  float* Cm   = (float*)(ws + (16ull << 20));// 32 MB  C = yW  [4096,2048] f32
  f16*   DsA  = (f16*)(ws + (48ull << 20));  // 16 MB  d scaled fp16 (ping)
  f16*   DsB  = (f16*)(ws + (64ull << 20));  // 16 MB  (pong)
  // precompute temps aliased over DsA region (dead before Ds1 is written):
  f16* Wth  = (f16*)(ws + (48ull << 20));    // 2 MB  W^T hi   [2048,512]
  f16* Wtlx = (f16*)(ws + (50ull << 20));    // 2 MB  W^T lo*256
  f16* Ath  = (f16*)(ws + (52ull << 20));    // 2 MB  A^T hi   [2048,512]
  f16* Atlx = (f16*)(ws + (54ull << 20));    // 2 MB  A^T lo*256
  f16* yh   = (f16*)(ws + (56ull << 20));    // 4 MB  y hi     [4096,512]
  f16* ylx  = (f16*)(ws + (60ull << 20));    // 4 MB  y lo*256

  trans_split<<<dim3(32, 8), 256, 0, stream>>>(A, Ath, Atlx);
  trans_split<<<dim3(32, 8), 256, 0, stream>>>(W, Wth, Wtlx);
  split_y<<<(BATCHN * MDIM) / 256, 256, 0, stream>>>(y, yh, ylx);

  // P^T[j][i] = sum_m W[m,j] A[m,i] = Wt @ At^T  (split-3, K=512) -> Pht/Plxt
  gemm_tn<0><<<dim3(16, 16), 256, 0, stream>>>(
      Wth, Atlx, Wtlx, Ath, Wth, Ath, MDIM,
      nullptr, Pht, Plxt, nullptr, nullptr, nullptr, nullptr, 0,
      0.f, 0.f, 0.f, nullptr, nullptr);

  // C = y @ W  (split-3, K=512) -> f32
  gemm_tn<1><<<dim3(16, 32), 256, 0, stream>>>(
      yh, Wtlx, ylx, Wth, yh, Wth, MDIM,
      Cm, nullptr, nullptr, nullptr, nullptr, nullptr, nullptr, 0,
      0.f, 0.f, 0.f, nullptr, nullptr);

  alista_iter0<<<(BATCHN * NDIM) / 256, 256, 0, stream>>>(Cm, thr, step, out, DsA);

  // iterations 1..15: acc = Ds@Pht ~= d_k P / sigma ; fused soft-threshold epilogue
  f16* cur = DsA;
  f16* nxt = DsB;
  float sigma = 1.0f;  // sigma_k = 4^(k-1)
  for (int it = 1; it < NITER; ++it) {
    gemm_tn<2><<<dim3(512), 256, 0, stream>>>(
        cur, Pht, nullptr, nullptr, nullptr, nullptr, NDIM,
        nullptr, nullptr, nullptr, cur, Cm, thr, step, it,
        sigma, 1.0f / sigma, 0.25f / sigma, out, nxt);
    sigma *= 4.0f;
    f16* tmp = cur; cur = nxt; nxt = tmp;
  }
}

// Round 3
// 892.421 us; speedup vs baseline: 1.8554x; 1.1727x over previous
//
#include <hip/hip_runtime.h>

// ALISTA on MI355X.
// d_{k+1} = soft(d_k - s*(d_k @ P - C), thr_k),  P = A^T W [2048x2048], C = y W [4096x2048]
// R3: iteration GEMM rebuilt as deep-pipelined 256x128 tile, BK=32, 8 waves,
//     quad-buffered LDS, counted vmcnt(3), T2 XOR swizzle, T5 setprio, XCD swizzle.
// P single-pass fp16 (R2-verified); d_k carried as fp16 scaled by 4^-(k-1).

#define NDIM 2048
#define MDIM 512
#define BATCHN 4096
#define NITER 16
#define BM 128
#define BN 128
#define BK 64

#define BM2 256
#define BN2 128
#define BK2 32
#define NKT (NDIM / BK2)   // 64 K-tiles

typedef _Float16 f16;
typedef f16 f16x8 __attribute__((ext_vector_type(8)));
typedef float f32x4 __attribute__((ext_vector_type(4)));

__device__ __forceinline__ void gload_lds16(const void* g, void* lds) {
  __builtin_amdgcn_global_load_lds(
      (const __attribute__((address_space(1))) unsigned int*)g,
      (__attribute__((address_space(3))) unsigned int*)lds, 16, 0, 0);
}

// ---------------- R3 iteration GEMM: 256x128, BK=32, quad-buffered, counted vmcnt ---------
// A = Ds [4096][2048] f16 (K-contig), B = Pht [2048][2048] f16 (K-contig).
__global__ __launch_bounds__(512, 2) void alista_iter_gemm(
    const f16* __restrict__ Ds, const f16* __restrict__ P,
    const float* __restrict__ Cmat,
    const float* __restrict__ thr, const float* __restrict__ step, int it,
    float sigma, float inv_sigma, float inv_sigma_next,
    float* __restrict__ outIter, f16* __restrict__ DsNext)
{
  __shared__ __align__(16) f16 ldsA[4 * BM2 * BK2];  // 64 KB
  __shared__ __align__(16) f16 ldsB[4 * BN2 * BK2];  // 32 KB

  const int tid = threadIdx.x;
  const int w = tid >> 6, l = tid & 63;
  const int wm = w >> 1, wn = w & 1;      // 4M x 2N waves, per-wave 64x64
  const int h = l >> 4;                    // k-octet selector

  // XCD-aware swizzle over 256 blocks (256 % 8 == 0)
  const int bid = blockIdx.x;
  const int wgid = (bid & 7) * 32 + (bid >> 3);
  const int rowTile = (wgid >> 4) * BM2;   // 16 row tiles
  const int colTile = (wgid & 15) * BN2;   // 16 col tiles

  const f16* Abase = Ds + (size_t)rowTile * NDIM;
  const f16* Bbase = P + (size_t)colTile * NDIM;

  // staging for K-tile t into buf t&3. 3 global_load_lds per thread.
  // LDS linear: A byte o = r*8192 + w*1024 + l*16 -> row = r*128 + tid/4.
  // T2: LDS holds swizzled layout; source column pre-swizzled (rule #21).
  auto stage = [&](int t) {
    const int buf = t & 3;
#pragma unroll
    for (int r = 0; r < 2; ++r) {  // A tile 256x32 = 2 rounds
      int row = r * 128 + (tid >> 2);
      int colb = ((tid & 3) << 4) ^ ((row & 3) << 4);
      gload_lds16((const char*)(Abase + (size_t)row * NDIM + t * BK2) + colb,
                  (char*)ldsA + buf * 16384 + r * 8192 + w * 1024);
    }
    {  // B tile 128x32 = 1 round
      int row = tid >> 2;
      int colb = ((tid & 3) << 4) ^ ((row & 3) << 4);
      gload_lds16((const char*)(Bbase + (size_t)row * NDIM + t * BK2) + colb,
                  (char*)ldsB + buf * 8192 + w * 1024);
    }
  };

  // prologue: tiles 0,1 in flight; wait tile 0 (3 of 6 outstanding retire)
  stage(0);
  stage(1);
  asm volatile("s_waitcnt vmcnt(3)" ::: "memory");
  __builtin_amdgcn_s_barrier();
  __builtin_amdgcn_sched_barrier(0);

  f32x4 acc[4][4] = {};

  for (int t = 0; t < NKT; ++t) {
    const f16* bA = ldsA + (t & 3) * 8192;  // element offsets
    const f16* bB = ldsB + (t & 3) * 4096;

    // fragment ds_reads (swizzled addresses)
    f16x8 af[4], bf[4];
#pragma unroll
    for (int m = 0; m < 4; ++m) {
      int row = wm * 64 + m * 16 + (l & 15);
      af[m] = *(const f16x8*)(bA + row * 32 + ((h ^ (row & 3)) << 3));
    }
#pragma unroll
    for (int n = 0; n < 4; ++n) {
      int row = wn * 64 + n * 16 + (l & 15);
      bf[n] = *(const f16x8*)(bB + row * 32 + ((h ^ (row & 3)) << 3));
    }

    // prefetch tile t+2 (writes buf (t+2)&3; readers are on t&3, t+1 lands in (t+1)&3)
    if (t + 2 < NKT) stage(t + 2);

    __builtin_amdgcn_s_barrier();   // phase lock before MFMA cluster
    __builtin_amdgcn_s_setprio(1);
#pragma unroll
    for (int m = 0; m < 4; ++m)
#pragma unroll
      for (int n = 0; n < 4; ++n)
        acc[m][n] = __builtin_amdgcn_mfma_f32_16x16x32_f16(af[m], bf[n], acc[m][n], 0, 0, 0);
    __builtin_amdgcn_s_setprio(0);

    if (t < NKT - 1) {
      // boundary: ensure tile t+1 fully in LDS. Steady state: allow t+2's 3 loads in flight.
      if (t + 2 < NKT) asm volatile("s_waitcnt vmcnt(3)" ::: "memory");
      else             asm volatile("s_waitcnt vmcnt(0)" ::: "memory");
      __builtin_amdgcn_s_barrier();
      __builtin_amdgcn_sched_barrier(0);
    }
  }

  // fused ALISTA epilogue. C/D layout: col = lane&15, row = 4*(lane>>4) + reg
  const int baseRow = rowTile + wm * 64 + (h << 2);
  const int baseCol = colTile + wn * 64 + (l & 15);
  const float s = step[it];
  const float tt = thr[it];
  const size_t itOff = (size_t)it * (size_t)BATCHN * NDIM;
#pragma unroll
  for (int m = 0; m < 4; ++m)
#pragma unroll
    for (int n = 0; n < 4; ++n)
#pragma unroll
      for (int r = 0; r < 4; ++r) {
        int row = baseRow + m * 16 + r;
        int col = baseCol + n * 16;
        size_t g = (size_t)row * NDIM + col;
        float v = acc[m][n][r];
        float ds = (float)Ds[g];
        float cv = Cmat[g];
        float z = sigma * (ds - s * (v - cv * inv_sigma));
        float az = __builtin_fabsf(z) - tt;
        float dn = az > 0.f ? (z > 0.f ? az : -az) : 0.f;
        outIter[itOff + g] = dn;
        DsNext[g] = (f16)(dn * inv_sigma_next);
      }
}

// ---------------- precompute GEMM (proven R1 structure, split-3 fp16) ----------------
__device__ __forceinline__ void gemm_pass(
    const f16* __restrict__ Ap, const f16* __restrict__ Bp, int K,
    int rowTile, int colTile, int t, int w, int l, int wr, int wc,
    f16* ldsA, f16* ldsB, f32x4 (&acc)[4][4])
{
  const f16* Arow = Ap + (size_t)rowTile * K;
  const f16* Brow = Bp + (size_t)colTile * K;
  for (int kt = 0; kt < K; kt += BK) {
    __syncthreads();
#pragma unroll
    for (int n = 0; n < 4; ++n) {
      int e = n * 2048 + t * 8;
      int r = e >> 6, c = e & 63;
      gload_lds16(Arow + (size_t)r * K + kt + c, (char*)ldsA + n * 4096 + w * 1024);
    }
#pragma unroll
    for (int n = 0; n < 4; ++n) {
      int e = n * 2048 + t * 8;
      int r = e >> 6, c = e & 63;
      gload_lds16(Brow + (size_t)r * K + kt + c, (char*)ldsB + n * 4096 + w * 1024);
    }
    asm volatile("s_waitcnt vmcnt(0)" ::: "memory");
    __syncthreads();
#pragma unroll
    for (int ks = 0; ks < 2; ++ks) {
      f16x8 a[4], b[4];
#pragma unroll
      for (int m = 0; m < 4; ++m)
        a[m] = *(const f16x8*)(ldsA + ((wr * 64 + m * 16 + (l & 15)) * BK + ks * 32 + (l >> 4) * 8));
#pragma unroll
      for (int n = 0; n < 4; ++n)
        b[n] = *(const f16x8*)(ldsB + ((wc * 64 + n * 16 + (l & 15)) * BK + ks * 32 + (l >> 4) * 8));
#pragma unroll
      for (int m = 0; m < 4; ++m)
#pragma unroll
        for (int n = 0; n < 4; ++n)
          acc[m][n] = __builtin_amdgcn_mfma_f32_16x16x32_f16(a[m], b[n], acc[m][n], 0, 0, 0);
    }
  }
}

// EPI 0: write fp16 split pair (Ph, 256*Pl).  EPI 1: write f32.
template <int EPI>
__global__ __launch_bounds__(256, 2) void gemm_tn(
    const f16* __restrict__ A0, const f16* __restrict__ B0,
    const f16* __restrict__ A1, const f16* __restrict__ B1,
    const f16* __restrict__ A2, const f16* __restrict__ B2,
    int K,
    float* __restrict__ outF, f16* __restrict__ outH, f16* __restrict__ outLx)
{
  __shared__ __align__(16) f16 ldsA[BM * BK];
  __shared__ __align__(16) f16 ldsB[BN * BK];
  int t = threadIdx.x;
  int w = t >> 6, l = t & 63;
  int wr = w >> 1, wc = w & 1;
  int rowTile = blockIdx.y * BM;
  int colTile = blockIdx.x * BN;

  f32x4 acc[4][4] = {};
  gemm_pass(A0, B0, K, rowTile, colTile, t, w, l, wr, wc, ldsA, ldsB, acc);
  gemm_pass(A1, B1, K, rowTile, colTile, t, w, l, wr, wc, ldsA, ldsB, acc);
#pragma unroll
  for (int m = 0; m < 4; ++m)
#pragma unroll
    for (int n = 0; n < 4; ++n)
      acc[m][n] *= (1.0f / 256.0f);
  gemm_pass(A2, B2, K, rowTile, colTile, t, w, l, wr, wc, ldsA, ldsB, acc);

  int baseRow = rowTile + wr * 64 + ((l >> 4) << 2);
  int baseCol = colTile + wc * 64 + (l & 15);
#pragma unroll
  for (int m = 0; m < 4; ++m)
#pragma unroll
    for (int n = 0; n < 4; ++n)
#pragma unroll
      for (int r = 0; r < 4; ++r) {
        int row = baseRow + m * 16 + r;
        int col = baseCol + n * 16;
        size_t g = (size_t)row * NDIM + col;
        float v = acc[m][n][r];
        if (EPI == 0) {
          f16 hh = (f16)v;
          outH[g] = hh;
          outLx[g] = (f16)((v - (float)hh) * 256.0f);
        } else {
          outF[g] = v;
        }
      }
}

// in [512,2048] f32 -> transposed fp16 splits [2048,512]: oh + olx/256
__global__ __launch_bounds__(256) void trans_split(
    const float* __restrict__ in, f16* __restrict__ oh, f16* __restrict__ olx)
{
  __shared__ float tile[64][65];
  int t = threadIdx.x;
  int tr = t >> 6;
  int tc = t & 63;
  int r0 = blockIdx.y * 64;
  int c0 = blockIdx.x * 64;
#pragma unroll
  for (int i = 0; i < 16; ++i) {
    int r = i * 4 + tr;
    tile[r][tc] = in[(size_t)(r0 + r) * NDIM + c0 + tc];
  }
  __syncthreads();
#pragma unroll
  for (int i = 0; i < 16; ++i) {
    int r = i * 4 + tr;
    float v = tile[tc][r];
    f16 hh = (f16)v;
    size_t o = (size_t)(c0 + r) * MDIM + r0 + tc;
    oh[o] = hh;
    olx[o] = (f16)((v - (float)hh) * 256.0f);
  }
}

__global__ __launch_bounds__(256) void split_y(
    const float* __restrict__ in, f16* __restrict__ oh, f16* __restrict__ olx)
{
  size_t i = (size_t)blockIdx.x * 256 + threadIdx.x;
  float v = in[i];
  f16 hh = (f16)v;
  oh[i] = hh;
  olx[i] = (f16)((v - (float)hh) * 256.0f);
}

__global__ __launch_bounds__(256) void alista_iter0(
    const float* __restrict__ Cmat, const float* __restrict__ thr,
    const float* __restrict__ step, float* __restrict__ out, f16* __restrict__ Ds1)
{
  size_t i = (size_t)blockIdx.x * 256 + threadIdx.x;
  float s = step[0], tt = thr[0];
  float z = s * Cmat[i];
  float az = __builtin_fabsf(z) - tt;
  float dn = az > 0.f ? (z > 0.f ? az : -az) : 0.f;
  out[i] = dn;
  Ds1[i] = (f16)dn;
}

extern "C" void kernel_launch(void* const* d_in, const int* in_sizes, int n_in,
                              void* d_out, int out_size, void* d_ws, size_t ws_size,
                              hipStream_t stream)
{
  const float* y    = (const float*)d_in[0];
  const float* A    = (const float*)d_in[1];
  const float* W    = (const float*)d_in[2];
  const float* thr  = (const float*)d_in[3];
  const float* step = (const float*)d_in[4];
  float* out = (float*)d_out;
  char* ws = (char*)d_ws;

  f16*   Pht  = (f16*)(ws + 0);              // 8 MB   P^T hi  [2048,2048]
  f16*   Plxt = (f16*)(ws + (8ull  << 20));  // 8 MB   P^T lo*256 (EPI0 byproduct)
  float* Cm   = (float*)(ws + (16ull << 20));// 32 MB  C = yW  [4096,2048] f32
  f16*   DsA  = (f16*)(ws + (48ull << 20));  // 16 MB  d scaled fp16 (ping)
  f16*   DsB  = (f16*)(ws + (64ull << 20));  // 16 MB  (pong)
  f16* Wth  = (f16*)(ws + (48ull << 20));    // precompute temps alias DsA (dead before Ds1)
  f16* Wtlx = (f16*)(ws + (50ull << 20));
  f16* Ath  = (f16*)(ws + (52ull << 20));
  f16* Atlx = (f16*)(ws + (54ull << 20));
  f16* yh   = (f16*)(ws + (56ull << 20));
  f16* ylx  = (f16*)(ws + (60ull << 20));

  trans_split<<<dim3(32, 8), 256, 0, stream>>>(A, Ath, Atlx);
  trans_split<<<dim3(32, 8), 256, 0, stream>>>(W, Wth, Wtlx);
  split_y<<<(BATCHN * MDIM) / 256, 256, 0, stream>>>(y, yh, ylx);

  gemm_tn<0><<<dim3(16, 16), 256, 0, stream>>>(
      Wth, Atlx, Wtlx, Ath, Wth, Ath, MDIM, nullptr, Pht, Plxt);

  gemm_tn<1><<<dim3(16, 32), 256, 0, stream>>>(
      yh, Wtlx, ylx, Wth, yh, Wth, MDIM, Cm, nullptr, nullptr);

  alista_iter0<<<(BATCHN * NDIM) / 256, 256, 0, stream>>>(Cm, thr, step, out, DsA);

  f16* cur = DsA;
  f16* nxt = DsB;
  float sigma = 1.0f;  // sigma_k = 4^(k-1)
  for (int it = 1; it < NITER; ++it) {
    alista_iter_gemm<<<dim3(256), 512, 0, stream>>>(
        cur, Pht, Cm, thr, step, it,
        sigma, 1.0f / sigma, 0.25f / sigma, out, nxt);
    sigma *= 4.0f;
    f16* tmp = cur; cur = nxt; nxt = tmp;
  }
}

// Round 4
// 828.145 us; speedup vs baseline: 1.9994x; 1.0776x over previous
//
#include <hip/hip_runtime.h>

// ALISTA on MI355X.
// d_{k+1} = soft(d_k - s*(d_k @ P - C), thr_k),  P = A^T W [2048x2048], C = y W [4096x2048]
// R4: iteration GEMM adds register fragment double-buffering (ds_read of tile t+1
//     overlaps MFMA of tile t), 1 barrier/tile, counted vmcnt; C stored as f16.
// P single-pass fp16; d_k carried as fp16 scaled by 4^-(k-1).

#define NDIM 2048
#define MDIM 512
#define BATCHN 4096
#define NITER 16
#define BM 128
#define BN 128
#define BK 64

#define BM2 256
#define BN2 128
#define BK2 32
#define NKT (NDIM / BK2)   // 64 K-tiles

typedef _Float16 f16;
typedef f16 f16x8 __attribute__((ext_vector_type(8)));
typedef float f32x4 __attribute__((ext_vector_type(4)));

__device__ __forceinline__ void gload_lds16(const void* g, void* lds) {
  __builtin_amdgcn_global_load_lds(
      (const __attribute__((address_space(1))) unsigned int*)g,
      (__attribute__((address_space(3))) unsigned int*)lds, 16, 0, 0);
}

// ---------------- R4 iteration GEMM: 256x128, BK=32, quad-buffered LDS, reg-dbuf frags ----
// A = Ds [4096][2048] f16 (K-contig), B = P [2048][2048] f16 (K-contig).
__global__ __launch_bounds__(512, 2) void alista_iter_gemm(
    const f16* __restrict__ Ds, const f16* __restrict__ P,
    const f16* __restrict__ Ch,
    const float* __restrict__ thr, const float* __restrict__ step, int it,
    float sigma, float inv_sigma, float inv_sigma_next,
    float* __restrict__ outIter, f16* __restrict__ DsNext)
{
  __shared__ __align__(16) f16 ldsA[4 * BM2 * BK2];  // 64 KB
  __shared__ __align__(16) f16 ldsB[4 * BN2 * BK2];  // 32 KB

  const int tid = threadIdx.x;
  const int w = tid >> 6, l = tid & 63;
  const int wm = w >> 1, wn = w & 1;      // 4M x 2N waves, per-wave 64x64
  const int h = l >> 4;                   // k-octet selector

  // XCD-aware swizzle over 256 blocks (256 % 8 == 0)
  const int bid = blockIdx.x;
  const int wgid = (bid & 7) * 32 + (bid >> 3);
  const int rowTile = (wgid >> 4) * BM2;   // 16 row tiles
  const int colTile = (wgid & 15) * BN2;   // 16 col tiles

  const f16* Abase = Ds + (size_t)rowTile * NDIM;
  const f16* Bbase = P + (size_t)colTile * NDIM;

  // stage K-tile t into buf t&3 (3 global_load_lds / thread).
  // T2 swizzle: linear LDS dest, source column pre-swizzled (rule #21).
  auto stage = [&](int t) {
    const int buf = t & 3;
#pragma unroll
    for (int r = 0; r < 2; ++r) {  // A tile 256x32
      int row = r * 128 + (tid >> 2);
      int colb = ((tid & 3) << 4) ^ ((row & 3) << 4);
      gload_lds16((const char*)(Abase + (size_t)row * NDIM + t * BK2) + colb,
                  (char*)ldsA + buf * 16384 + r * 8192 + w * 1024);
    }
    {  // B tile 128x32
      int row = tid >> 2;
      int colb = ((tid & 3) << 4) ^ ((row & 3) << 4);
      gload_lds16((const char*)(Bbase + (size_t)row * NDIM + t * BK2) + colb,
                  (char*)ldsB + buf * 8192 + w * 1024);
    }
  };

// fragment reads from buf (t&3) with swizzled addresses into named regs
#define READ_FRAGS(t, af, bf)                                                   \
  {                                                                             \
    const f16* bA_ = ldsA + ((t) & 3) * 8192;                                   \
    const f16* bB_ = ldsB + ((t) & 3) * 4096;                                   \
    _Pragma("unroll")                                                           \
    for (int m = 0; m < 4; ++m) {                                               \
      int row = wm * 64 + m * 16 + (l & 15);                                    \
      af[m] = *(const f16x8*)(bA_ + row * 32 + ((h ^ (row & 3)) << 3));         \
    }                                                                           \
    _Pragma("unroll")                                                           \
    for (int n = 0; n < 4; ++n) {                                               \
      int row = wn * 64 + n * 16 + (l & 15);                                    \
      bf[n] = *(const f16x8*)(bB_ + row * 32 + ((h ^ (row & 3)) << 3));         \
    }                                                                           \
  }

#define MFMA_CLUSTER(af, bf)                                                    \
  __builtin_amdgcn_s_setprio(1);                                                \
  _Pragma("unroll")                                                             \
  for (int m = 0; m < 4; ++m)                                                   \
    _Pragma("unroll")                                                           \
    for (int n = 0; n < 4; ++n)                                                 \
      acc[m][n] = __builtin_amdgcn_mfma_f32_16x16x32_f16(af[m], bf[n],          \
                                                         acc[m][n], 0, 0, 0);   \
  __builtin_amdgcn_s_setprio(0);

  // prologue: tiles 0,1 staged; wait tile 0; read frags 0; stage 2; wait tile 1
  stage(0);
  stage(1);
  asm volatile("s_waitcnt vmcnt(3)" ::: "memory");   // tile 0 landed
  __builtin_amdgcn_s_barrier();

  f32x4 acc[4][4] = {};
  f16x8 afE[4], bfE[4], afO[4], bfO[4];   // even/odd register sets

  READ_FRAGS(0, afE, bfE);
  stage(2);
  asm volatile("s_waitcnt vmcnt(3)" ::: "memory");   // tile 1 landed (tile 2 in flight)
  __builtin_amdgcn_s_barrier();
  __builtin_amdgcn_sched_barrier(0);

  // invariant at top of iter t (even): frags t in E-regs; LDS has t+1 landed; t+2 in flight
  for (int t = 0; t < NKT; t += 2) {
    // ---- half 1: MFMA tile t (E), read frags t+1 (O), stage t+3 ----
    READ_FRAGS(t + 1, afO, bfO);
    if (t + 3 < NKT) stage(t + 3);       // overwrites buf (t-1)&3: reads drained pre-barrier
    __builtin_amdgcn_sched_barrier(0);
    MFMA_CLUSTER(afE, bfE);
    if (t + 3 < NKT) asm volatile("s_waitcnt vmcnt(3)" ::: "memory");  // t+2 landed
    else             asm volatile("s_waitcnt vmcnt(0)" ::: "memory");
    __builtin_amdgcn_s_barrier();
    __builtin_amdgcn_sched_barrier(0);

    // ---- half 2: MFMA tile t+1 (O), read frags t+2 (E), stage t+4 ----
    if (t + 2 < NKT) READ_FRAGS(t + 2, afE, bfE);
    if (t + 4 < NKT) stage(t + 4);       // overwrites buf t&3: reads drained pre-barrier
    __builtin_amdgcn_sched_barrier(0);
    MFMA_CLUSTER(afO, bfO);
    if (t + 4 < NKT) asm volatile("s_waitcnt vmcnt(3)" ::: "memory");  // t+3 landed
    else             asm volatile("s_waitcnt vmcnt(0)" ::: "memory");
    __builtin_amdgcn_s_barrier();
    __builtin_amdgcn_sched_barrier(0);
  }

  // fused ALISTA epilogue. C/D layout: col = lane&15, row = 4*(lane>>4) + reg
  const int baseRow = rowTile + wm * 64 + (h << 2);
  const int baseCol = colTile + wn * 64 + (l & 15);
  const float s = step[it];
  const float tt = thr[it];
  const size_t itOff = (size_t)it * (size_t)BATCHN * NDIM;
#pragma unroll
  for (int m = 0; m < 4; ++m)
#pragma unroll
    for (int n = 0; n < 4; ++n)
#pragma unroll
      for (int r = 0; r < 4; ++r) {
        int row = baseRow + m * 16 + r;
        int col = baseCol + n * 16;
        size_t g = (size_t)row * NDIM + col;
        float v = acc[m][n][r];
        float ds = (float)Ds[g];
        float cv = (float)Ch[g];
        float z = sigma * (ds - s * (v - cv * inv_sigma));
        float az = __builtin_fabsf(z) - tt;
        float dn = az > 0.f ? (z > 0.f ? az : -az) : 0.f;
        outIter[itOff + g] = dn;
        DsNext[g] = (f16)(dn * inv_sigma_next);
      }
#undef READ_FRAGS
#undef MFMA_CLUSTER
}

// ---------------- precompute GEMM (proven R1 structure, split-3 fp16) ----------------
__device__ __forceinline__ void gemm_pass(
    const f16* __restrict__ Ap, const f16* __restrict__ Bp, int K,
    int rowTile, int colTile, int t, int w, int l, int wr, int wc,
    f16* ldsA, f16* ldsB, f32x4 (&acc)[4][4])
{
  const f16* Arow = Ap + (size_t)rowTile * K;
  const f16* Brow = Bp + (size_t)colTile * K;
  for (int kt = 0; kt < K; kt += BK) {
    __syncthreads();
#pragma unroll
    for (int n = 0; n < 4; ++n) {
      int e = n * 2048 + t * 8;
      int r = e >> 6, c = e & 63;
      gload_lds16(Arow + (size_t)r * K + kt + c, (char*)ldsA + n * 4096 + w * 1024);
    }
#pragma unroll
    for (int n = 0; n < 4; ++n) {
      int e = n * 2048 + t * 8;
      int r = e >> 6, c = e & 63;
      gload_lds16(Brow + (size_t)r * K + kt + c, (char*)ldsB + n * 4096 + w * 1024);
    }
    asm volatile("s_waitcnt vmcnt(0)" ::: "memory");
    __syncthreads();
#pragma unroll
    for (int ks = 0; ks < 2; ++ks) {
      f16x8 a[4], b[4];
#pragma unroll
      for (int m = 0; m < 4; ++m)
        a[m] = *(const f16x8*)(ldsA + ((wr * 64 + m * 16 + (l & 15)) * BK + ks * 32 + (l >> 4) * 8));
#pragma unroll
      for (int n = 0; n < 4; ++n)
        b[n] = *(const f16x8*)(ldsB + ((wc * 64 + n * 16 + (l & 15)) * BK + ks * 32 + (l >> 4) * 8));
#pragma unroll
      for (int m = 0; m < 4; ++m)
#pragma unroll
        for (int n = 0; n < 4; ++n)
          acc[m][n] = __builtin_amdgcn_mfma_f32_16x16x32_f16(a[m], b[n], acc[m][n], 0, 0, 0);
    }
  }
}

// EPI 0: write fp16 split pair (Ph, 256*Pl).  EPI 1: write f16 only (C as f16).
template <int EPI>
__global__ __launch_bounds__(256, 2) void gemm_tn(
    const f16* __restrict__ A0, const f16* __restrict__ B0,
    const f16* __restrict__ A1, const f16* __restrict__ B1,
    const f16* __restrict__ A2, const f16* __restrict__ B2,
    int K,
    f16* __restrict__ outH, f16* __restrict__ outLx)
{
  __shared__ __align__(16) f16 ldsA[BM * BK];
  __shared__ __align__(16) f16 ldsB[BN * BK];
  int t = threadIdx.x;
  int w = t >> 6, l = t & 63;
  int wr = w >> 1, wc = w & 1;
  int rowTile = blockIdx.y * BM;
  int colTile = blockIdx.x * BN;

  f32x4 acc[4][4] = {};
  gemm_pass(A0, B0, K, rowTile, colTile, t, w, l, wr, wc, ldsA, ldsB, acc);
  gemm_pass(A1, B1, K, rowTile, colTile, t, w, l, wr, wc, ldsA, ldsB, acc);
#pragma unroll
  for (int m = 0; m < 4; ++m)
#pragma unroll
    for (int n = 0; n < 4; ++n)
      acc[m][n] *= (1.0f / 256.0f);
  gemm_pass(A2, B2, K, rowTile, colTile, t, w, l, wr, wc, ldsA, ldsB, acc);

  int baseRow = rowTile + wr * 64 + ((l >> 4) << 2);
  int baseCol = colTile + wc * 64 + (l & 15);
#pragma unroll
  for (int m = 0; m < 4; ++m)
#pragma unroll
    for (int n = 0; n < 4; ++n)
#pragma unroll
      for (int r = 0; r < 4; ++r) {
        int row = baseRow + m * 16 + r;
        int col = baseCol + n * 16;
        size_t g = (size_t)row * NDIM + col;
        float v = acc[m][n][r];
        if (EPI == 0) {
          f16 hh = (f16)v;
          outH[g] = hh;
          outLx[g] = (f16)((v - (float)hh) * 256.0f);
        } else {
          outH[g] = (f16)v;
        }
      }
}

// in [512,2048] f32 -> transposed fp16 splits [2048,512]: oh + olx/256
__global__ __launch_bounds__(256) void trans_split(
    const float* __restrict__ in, f16* __restrict__ oh, f16* __restrict__ olx)
{
  __shared__ float tile[64][65];
  int t = threadIdx.x;
  int tr = t >> 6;
  int tc = t & 63;
  int r0 = blockIdx.y * 64;
  int c0 = blockIdx.x * 64;
#pragma unroll
  for (int i = 0; i < 16; ++i) {
    int r = i * 4 + tr;
    tile[r][tc] = in[(size_t)(r0 + r) * NDIM + c0 + tc];
  }
  __syncthreads();
#pragma unroll
  for (int i = 0; i < 16; ++i) {
    int r = i * 4 + tr;
    float v = tile[tc][r];
    f16 hh = (f16)v;
    size_t o = (size_t)(c0 + r) * MDIM + r0 + tc;
    oh[o] = hh;
    olx[o] = (f16)((v - (float)hh) * 256.0f);
  }
}

__global__ __launch_bounds__(256) void split_y(
    const float* __restrict__ in, f16* __restrict__ oh, f16* __restrict__ olx)
{
  size_t i = (size_t)blockIdx.x * 256 + threadIdx.x;
  float v = in[i];
  f16 hh = (f16)v;
  oh[i] = hh;
  olx[i] = (f16)((v - (float)hh) * 256.0f);
}

// iterate 0: d1 = soft(s0*C, thr0); out[0] = d1; Ds1 = fp16(d1)  (sigma_1 = 1)
__global__ __launch_bounds__(256) void alista_iter0(
    const f16* __restrict__ Ch, const float* __restrict__ thr,
    const float* __restrict__ step, float* __restrict__ out, f16* __restrict__ Ds1)
{
  size_t i = (size_t)blockIdx.x * 256 + threadIdx.x;
  float s = step[0], tt = thr[0];
  float z = s * (float)Ch[i];
  float az = __builtin_fabsf(z) - tt;
  float dn = az > 0.f ? (z > 0.f ? az : -az) : 0.f;
  out[i] = dn;
  Ds1[i] = (f16)dn;
}

extern "C" void kernel_launch(void* const* d_in, const int* in_sizes, int n_in,
                              void* d_out, int out_size, void* d_ws, size_t ws_size,
                              hipStream_t stream)
{
  const float* y    = (const float*)d_in[0];
  const float* A    = (const float*)d_in[1];
  const float* W    = (const float*)d_in[2];
  const float* thr  = (const float*)d_in[3];
  const float* step = (const float*)d_in[4];
  float* out = (float*)d_out;
  char* ws = (char*)d_ws;

  // ws layout (64 MB):
  f16* Pht  = (f16*)(ws + 0);               // 8 MB   P^T hi  [2048,2048]
  f16* Plxt = (f16*)(ws + (8ull  << 20));   // 8 MB   P^T lo*256 (EPI0 byproduct)
  f16* Ch   = (f16*)(ws + (16ull << 20));   // 16 MB  C = yW  [4096,2048] f16
  f16* DsA  = (f16*)(ws + (32ull << 20));   // 16 MB  d scaled fp16 (ping)
  f16* DsB  = (f16*)(ws + (48ull << 20));   // 16 MB  (pong)
  // precompute temps alias DsA/DsB (dead before iter0/iter1 write them):
  f16* Wth  = (f16*)(ws + (32ull << 20));   // 2 MB  W^T hi   [2048,512]
  f16* Wtlx = (f16*)(ws + (34ull << 20));   // 2 MB  W^T lo*256
  f16* Ath  = (f16*)(ws + (36ull << 20));   // 2 MB  A^T hi   [2048,512]
  f16* Atlx = (f16*)(ws + (38ull << 20));   // 2 MB  A^T lo*256
  f16* yh   = (f16*)(ws + (48ull << 20));   // 4 MB  y hi     [4096,512]
  f16* ylx  = (f16*)(ws + (52ull << 20));   // 4 MB  y lo*256

  trans_split<<<dim3(32, 8), 256, 0, stream>>>(A, Ath, Atlx);
  trans_split<<<dim3(32, 8), 256, 0, stream>>>(W, Wth, Wtlx);
  split_y<<<(BATCHN * MDIM) / 256, 256, 0, stream>>>(y, yh, ylx);

  // P^T = Wt @ At^T (split-3, K=512) -> Pht (+Plxt byproduct)
  gemm_tn<0><<<dim3(16, 16), 256, 0, stream>>>(
      Wth, Atlx, Wtlx, Ath, Wth, Ath, MDIM, Pht, Plxt);

  // C = y @ W (split-3, K=512) -> f16
  gemm_tn<1><<<dim3(16, 32), 256, 0, stream>>>(
      yh, Wtlx, ylx, Wth, yh, Wth, MDIM, Ch, nullptr);

  alista_iter0<<<(BATCHN * NDIM) / 256, 256, 0, stream>>>(Ch, thr, step, out, DsA);

  f16* cur = DsA;
  f16* nxt = DsB;
  float sigma = 1.0f;  // sigma_k = 4^(k-1)
  for (int it = 1; it < NITER; ++it) {
    alista_iter_gemm<<<dim3(256), 512, 0, stream>>>(
        cur, Pht, Ch, thr, step, it,
        sigma, 1.0f / sigma, 0.25f / sigma, out, nxt);
    sigma *= 4.0f;
    f16* tmp = cur; cur = nxt; nxt = tmp;
  }
}

// Round 5
// 788.622 us; speedup vs baseline: 2.0996x; 1.0501x over previous
//
#include <hip/hip_runtime.h>

// ALISTA on MI355X.
// d_{k+1} = soft(d_k - s*(d_k @ P - C), thr_k),  P = A^T W [2048x2048], C = y W [4096x2048]
// R5: fix LDS XOR swizzle (row&3 -> (row>>1)&3: 4-way conflict -> free 2-way);
//     precompute P and C single-pass fp16 (error budget analyzed, ~0.9% total).
// P single-pass fp16; d_k carried as fp16 scaled by 4^-(k-1); C carried as f16.

#define NDIM 2048
#define MDIM 512
#define BATCHN 4096
#define NITER 16
#define BM 128
#define BN 128
#define BK 64

#define BM2 256
#define BN2 128
#define BK2 32
#define NKT (NDIM / BK2)   // 64 K-tiles

typedef _Float16 f16;
typedef f16 f16x8 __attribute__((ext_vector_type(8)));
typedef float f32x4 __attribute__((ext_vector_type(4)));

__device__ __forceinline__ void gload_lds16(const void* g, void* lds) {
  __builtin_amdgcn_global_load_lds(
      (const __attribute__((address_space(1))) unsigned int*)g,
      (__attribute__((address_space(3))) unsigned int*)lds, 16, 0, 0);
}

// ---------------- iteration GEMM: 256x128, BK=32, quad-buffered LDS, reg-dbuf frags ----
// A = Ds [4096][2048] f16 (K-contig), B = P [2048][2048] f16 (K-contig).
__global__ __launch_bounds__(512, 2) void alista_iter_gemm(
    const f16* __restrict__ Ds, const f16* __restrict__ P,
    const f16* __restrict__ Ch,
    const float* __restrict__ thr, const float* __restrict__ step, int it,
    float sigma, float inv_sigma, float inv_sigma_next,
    float* __restrict__ outIter, f16* __restrict__ DsNext)
{
  __shared__ __align__(16) f16 ldsA[4 * BM2 * BK2];  // 64 KB
  __shared__ __align__(16) f16 ldsB[4 * BN2 * BK2];  // 32 KB

  const int tid = threadIdx.x;
  const int w = tid >> 6, l = tid & 63;
  const int wm = w >> 1, wn = w & 1;      // 4M x 2N waves, per-wave 64x64
  const int h = l >> 4;                   // k-octet selector

  // XCD-aware swizzle over 256 blocks (256 % 8 == 0)
  const int bid = blockIdx.x;
  const int wgid = (bid & 7) * 32 + (bid >> 3);
  const int rowTile = (wgid >> 4) * BM2;   // 16 row tiles
  const int colTile = (wgid & 15) * BN2;   // 16 col tiles

  const f16* Abase = Ds + (size_t)rowTile * NDIM;
  const f16* Bbase = P + (size_t)colTile * NDIM;

  // stage K-tile t into buf t&3 (3 global_load_lds / thread).
  // T2 swizzle: linear LDS dest, source granule pre-swizzled with the SAME
  // involution used on reads (rule #21).  Swizzle s = (row>>1)&3 so that
  // within a 16-lane read phase only lanes r,r+8 share a bank window (2-way, free).
  auto stage = [&](int t) {
    const int buf = t & 3;
#pragma unroll
    for (int r = 0; r < 2; ++r) {  // A tile 256x32
      int row = r * 128 + (tid >> 2);
      int colb = ((tid & 3) << 4) ^ (((row >> 1) & 3) << 4);
      gload_lds16((const char*)(Abase + (size_t)row * NDIM + t * BK2) + colb,
                  (char*)ldsA + buf * 16384 + r * 8192 + w * 1024);
    }
    {  // B tile 128x32
      int row = tid >> 2;
      int colb = ((tid & 3) << 4) ^ (((row >> 1) & 3) << 4);
      gload_lds16((const char*)(Bbase + (size_t)row * NDIM + t * BK2) + colb,
                  (char*)ldsB + buf * 8192 + w * 1024);
    }
  };

// fragment reads from buf (t&3) with swizzled addresses into named regs
#define READ_FRAGS(t, af, bf)                                                   \
  {                                                                             \
    const f16* bA_ = ldsA + ((t) & 3) * 8192;                                   \
    const f16* bB_ = ldsB + ((t) & 3) * 4096;                                   \
    _Pragma("unroll")                                                           \
    for (int m = 0; m < 4; ++m) {                                               \
      int row = wm * 64 + m * 16 + (l & 15);                                    \
      af[m] = *(const f16x8*)(bA_ + row * 32 + ((h ^ ((row >> 1) & 3)) << 3));  \
    }                                                                           \
    _Pragma("unroll")                                                           \
    for (int n = 0; n < 4; ++n) {                                               \
      int row = wn * 64 + n * 16 + (l & 15);                                    \
      bf[n] = *(const f16x8*)(bB_ + row * 32 + ((h ^ ((row >> 1) & 3)) << 3));  \
    }                                                                           \
  }

#define MFMA_CLUSTER(af, bf)                                                    \
  __builtin_amdgcn_s_setprio(1);                                                \
  _Pragma("unroll")                                                             \
  for (int m = 0; m < 4; ++m)                                                   \
    _Pragma("unroll")                                                           \
    for (int n = 0; n < 4; ++n)                                                 \
      acc[m][n] = __builtin_amdgcn_mfma_f32_16x16x32_f16(af[m], bf[n],          \
                                                         acc[m][n], 0, 0, 0);   \
  __builtin_amdgcn_s_setprio(0);

  // prologue: tiles 0,1 staged; wait tile 0; read frags 0; stage 2; wait tile 1
  stage(0);
  stage(1);
  asm volatile("s_waitcnt vmcnt(3)" ::: "memory");   // tile 0 landed
  __builtin_amdgcn_s_barrier();

  f32x4 acc[4][4] = {};
  f16x8 afE[4], bfE[4], afO[4], bfO[4];   // even/odd register sets

  READ_FRAGS(0, afE, bfE);
  stage(2);
  asm volatile("s_waitcnt vmcnt(3)" ::: "memory");   // tile 1 landed (tile 2 in flight)
  __builtin_amdgcn_s_barrier();
  __builtin_amdgcn_sched_barrier(0);

  // invariant at top of iter t (even): frags t in E-regs; LDS has t+1 landed; t+2 in flight
  for (int t = 0; t < NKT; t += 2) {
    // ---- half 1: MFMA tile t (E), read frags t+1 (O), stage t+3 ----
    READ_FRAGS(t + 1, afO, bfO);
    if (t + 3 < NKT) stage(t + 3);       // overwrites buf (t-1)&3: reads drained pre-barrier
    __builtin_amdgcn_sched_barrier(0);
    MFMA_CLUSTER(afE, bfE);
    if (t + 3 < NKT) asm volatile("s_waitcnt vmcnt(3)" ::: "memory");  // t+2 landed
    else             asm volatile("s_waitcnt vmcnt(0)" ::: "memory");
    __builtin_amdgcn_s_barrier();
    __builtin_amdgcn_sched_barrier(0);

    // ---- half 2: MFMA tile t+1 (O), read frags t+2 (E), stage t+4 ----
    if (t + 2 < NKT) READ_FRAGS(t + 2, afE, bfE);
    if (t + 4 < NKT) stage(t + 4);       // overwrites buf t&3: reads drained pre-barrier
    __builtin_amdgcn_sched_barrier(0);
    MFMA_CLUSTER(afO, bfO);
    if (t + 4 < NKT) asm volatile("s_waitcnt vmcnt(3)" ::: "memory");  // t+3 landed
    else             asm volatile("s_waitcnt vmcnt(0)" ::: "memory");
    __builtin_amdgcn_s_barrier();
    __builtin_amdgcn_sched_barrier(0);
  }

  // fused ALISTA epilogue. C/D layout: col = lane&15, row = 4*(lane>>4) + reg
  const int baseRow = rowTile + wm * 64 + (h << 2);
  const int baseCol = colTile + wn * 64 + (l & 15);
  const float s = step[it];
  const float tt = thr[it];
  const size_t itOff = (size_t)it * (size_t)BATCHN * NDIM;
#pragma unroll
  for (int m = 0; m < 4; ++m)
#pragma unroll
    for (int n = 0; n < 4; ++n)
#pragma unroll
      for (int r = 0; r < 4; ++r) {
        int row = baseRow + m * 16 + r;
        int col = baseCol + n * 16;
        size_t g = (size_t)row * NDIM + col;
        float v = acc[m][n][r];
        float ds = (float)Ds[g];
        float cv = (float)Ch[g];
        float z = sigma * (ds - s * (v - cv * inv_sigma));
        float az = __builtin_fabsf(z) - tt;
        float dn = az > 0.f ? (z > 0.f ? az : -az) : 0.f;
        outIter[itOff + g] = dn;
        DsNext[g] = (f16)(dn * inv_sigma_next);
      }
#undef READ_FRAGS
#undef MFMA_CLUSTER
}

// ---------------- precompute GEMM (single-pass fp16, R1 structure) ----------------
// C[row,col] = sum_k A[row,k]*B[col,k]; A [M][K] f16 K-contig, B [N][K] f16 K-contig.
__global__ __launch_bounds__(256, 2) void gemm_pre(
    const f16* __restrict__ Ap, const f16* __restrict__ Bp, int K,
    f16* __restrict__ outH)
{
  __shared__ __align__(16) f16 ldsA[BM * BK];
  __shared__ __align__(16) f16 ldsB[BN * BK];
  int t = threadIdx.x;
  int w = t >> 6, l = t & 63;
  int wr = w >> 1, wc = w & 1;
  int rowTile = blockIdx.y * BM;
  int colTile = blockIdx.x * BN;

  f32x4 acc[4][4] = {};
  const f16* Arow = Ap + (size_t)rowTile * K;
  const f16* Brow = Bp + (size_t)colTile * K;
  for (int kt = 0; kt < K; kt += BK) {
    __syncthreads();
#pragma unroll
    for (int n = 0; n < 4; ++n) {
      int e = n * 2048 + t * 8;
      int r = e >> 6, c = e & 63;
      gload_lds16(Arow + (size_t)r * K + kt + c, (char*)ldsA + n * 4096 + w * 1024);
    }
#pragma unroll
    for (int n = 0; n < 4; ++n) {
      int e = n * 2048 + t * 8;
      int r = e >> 6, c = e & 63;
      gload_lds16(Brow + (size_t)r * K + kt + c, (char*)ldsB + n * 4096 + w * 1024);
    }
    asm volatile("s_waitcnt vmcnt(0)" ::: "memory");
    __syncthreads();
#pragma unroll
    for (int ks = 0; ks < 2; ++ks) {
      f16x8 a[4], b[4];
#pragma unroll
      for (int m = 0; m < 4; ++m)
        a[m] = *(const f16x8*)(ldsA + ((wr * 64 + m * 16 + (l & 15)) * BK + ks * 32 + (l >> 4) * 8));
#pragma unroll
      for (int n = 0; n < 4; ++n)
        b[n] = *(const f16x8*)(ldsB + ((wc * 64 + n * 16 + (l & 15)) * BK + ks * 32 + (l >> 4) * 8));
#pragma unroll
      for (int m = 0; m < 4; ++m)
#pragma unroll
        for (int n = 0; n < 4; ++n)
          acc[m][n] = __builtin_amdgcn_mfma_f32_16x16x32_f16(a[m], b[n], acc[m][n], 0, 0, 0);
    }
  }

  int baseRow = rowTile + wr * 64 + ((l >> 4) << 2);
  int baseCol = colTile + wc * 64 + (l & 15);
#pragma unroll
  for (int m = 0; m < 4; ++m)
#pragma unroll
    for (int n = 0; n < 4; ++n)
#pragma unroll
      for (int r = 0; r < 4; ++r) {
        size_t g = (size_t)(baseRow + m * 16 + r) * NDIM + baseCol + n * 16;
        outH[g] = (f16)acc[m][n][r];
      }
}

// in [512,2048] f32 -> transposed fp16 [2048,512]
__global__ __launch_bounds__(256) void trans_h(
    const float* __restrict__ in, f16* __restrict__ oh)
{
  __shared__ float tile[64][65];
  int t = threadIdx.x;
  int tr = t >> 6;
  int tc = t & 63;
  int r0 = blockIdx.y * 64;
  int c0 = blockIdx.x * 64;
#pragma unroll
  for (int i = 0; i < 16; ++i) {
    int r = i * 4 + tr;
    tile[r][tc] = in[(size_t)(r0 + r) * NDIM + c0 + tc];
  }
  __syncthreads();
#pragma unroll
  for (int i = 0; i < 16; ++i) {
    int r = i * 4 + tr;
    oh[(size_t)(c0 + r) * MDIM + r0 + tc] = (f16)tile[tc][r];
  }
}

__global__ __launch_bounds__(256) void tofp16(
    const float* __restrict__ in, f16* __restrict__ oh)
{
  size_t i = (size_t)blockIdx.x * 256 + threadIdx.x;
  oh[i] = (f16)in[i];
}

// iterate 0: d1 = soft(s0*C, thr0); out[0] = d1; Ds1 = fp16(d1)  (sigma_1 = 1)
__global__ __launch_bounds__(256) void alista_iter0(
    const f16* __restrict__ Ch, const float* __restrict__ thr,
    const float* __restrict__ step, float* __restrict__ out, f16* __restrict__ Ds1)
{
  size_t i = (size_t)blockIdx.x * 256 + threadIdx.x;
  float s = step[0], tt = thr[0];
  float z = s * (float)Ch[i];
  float az = __builtin_fabsf(z) - tt;
  float dn = az > 0.f ? (z > 0.f ? az : -az) : 0.f;
  out[i] = dn;
  Ds1[i] = (f16)dn;
}

extern "C" void kernel_launch(void* const* d_in, const int* in_sizes, int n_in,
                              void* d_out, int out_size, void* d_ws, size_t ws_size,
                              hipStream_t stream)
{
  const float* y    = (const float*)d_in[0];
  const float* A    = (const float*)d_in[1];
  const float* W    = (const float*)d_in[2];
  const float* thr  = (const float*)d_in[3];
  const float* step = (const float*)d_in[4];
  float* out = (float*)d_out;
  char* ws = (char*)d_ws;

  // ws layout (64 MB):
  f16* Pht = (f16*)(ws + 0);                // 8 MB   P^T  [2048,2048] f16
  f16* Ch  = (f16*)(ws + (8ull  << 20));    // 16 MB  C = yW [4096,2048] f16
  f16* DsA = (f16*)(ws + (24ull << 20));    // 16 MB  d scaled fp16 (ping)
  f16* DsB = (f16*)(ws + (40ull << 20));    // 16 MB  (pong)
  // precompute temps alias DsA/DsB (dead before iter0/iter1 write them):
  f16* Wth = (f16*)(ws + (24ull << 20));    // 2 MB  W^T f16 [2048,512]
  f16* Ath = (f16*)(ws + (26ull << 20));    // 2 MB  A^T f16 [2048,512]
  f16* yh  = (f16*)(ws + (40ull << 20));    // 4 MB  y  f16 [4096,512]

  trans_h<<<dim3(32, 8), 256, 0, stream>>>(A, Ath);
  trans_h<<<dim3(32, 8), 256, 0, stream>>>(W, Wth);
  tofp16<<<(BATCHN * MDIM) / 256, 256, 0, stream>>>(y, yh);

  // P^T = Wt @ At^T (K=512) -> f16
  gemm_pre<<<dim3(16, 16), 256, 0, stream>>>(Wth, Ath, MDIM, Pht);
  // C = y @ W (K=512) -> f16
  gemm_pre<<<dim3(16, 32), 256, 0, stream>>>(yh, Wth, MDIM, Ch);

  alista_iter0<<<(BATCHN * NDIM) / 256, 256, 0, stream>>>(Ch, thr, step, out, DsA);

  f16* cur = DsA;
  f16* nxt = DsB;
  float sigma = 1.0f;  // sigma_k = 4^(k-1)
  for (int it = 1; it < NITER; ++it) {
    alista_iter_gemm<<<dim3(256), 512, 0, stream>>>(
        cur, Pht, Ch, thr, step, it,
        sigma, 1.0f / sigma, 0.25f / sigma, out, nxt);
    sigma *= 4.0f;
    f16* tmp = cur; cur = nxt; nxt = tmp;
  }
}